// Round 1
// baseline (82.157 us; speedup 1.0000x reference)
//
#include <hip/hip_runtime.h>

// ---------------------------------------------------------------------------
// QNNClassifier: 2-qubit StronglyEntanglingLayers + <Z0> + Linear(1,1)
//
// R4 design: two dispatches.
//   1) qnn_setup_kernel (1 wave): builds U, A = fc_w * Re(U^H D U), then
//      reduces the batch-shared quadratic form to 9 trig coefficients via
//      double-angle identities:
//        ev = (K0 + K1*cos x0 + K2*sin x0)
//           + cos x1 * (K3 + K4*cos x0 + K5*sin x0)
//           + sin x1 * (K6 + K7*cos x0 + K8*sin x0)
//      (fc_b folded into K0, fc_w folded into A). Writes K[9] to d_ws.
//   2) qnn_stream_kernel: pure streaming, 1 float4-out per thread
//      (2 float4 in, 8 sincos + 32 FMA, 1 float4 out). No per-thread form
//      rebuild -> low VGPR -> full occupancy; 2048 blocks covers n4 exactly.
//
// Fallback: if ws_size < 64 the fused single-kernel path (per-thread K build)
// is used instead.
// ---------------------------------------------------------------------------

struct C2 { float re, im; };
__device__ inline C2 cmul(C2 a, C2 b) { return {a.re*b.re - a.im*b.im, a.re*b.im + a.im*b.re}; }
__device__ inline C2 cadd(C2 a, C2 b) { return {a.re + b.re, a.im + b.im}; }

// Build the 9 trig coefficients K[0..8] (fc_w folded in, fc_b added to K0).
__device__ inline void qnn_build_K(const float* __restrict__ qp,
                                   const float* __restrict__ fc_w,
                                   const float* __restrict__ fc_b,
                                   float* __restrict__ K) {
    C2 U[4][4];
#pragma unroll
    for (int i = 0; i < 4; i++)
#pragma unroll
        for (int j = 0; j < 4; j++)
            U[i][j] = { (i == j) ? 1.f : 0.f, 0.f };

#pragma unroll
    for (int l = 0; l < 2; l++) {
        C2 r[2][2][2];  // [wire][row][col]
#pragma unroll
        for (int w = 0; w < 2; w++) {
            float phi = qp[(l*2 + w)*3 + 0];
            float th  = qp[(l*2 + w)*3 + 1];
            float om  = qp[(l*2 + w)*3 + 2];
            float c, s, epre, epim, emre, emim;
            __sincosf(0.5f * th, &s, &c);
            __sincosf(-0.5f * (phi + om), &epim, &epre);   // ep = e^{-i(phi+om)/2}
            __sincosf( 0.5f * (phi - om), &emim, &emre);   // em = e^{ i(phi-om)/2}
            r[w][0][0] = {  epre * c,  epim * c };
            r[w][0][1] = { -emre * s, -emim * s };
            r[w][1][0] = {  emre * s, -emim * s };   // conj(em)*s
            r[w][1][1] = {  epre * c, -epim * c };   // conj(ep)*c
        }
        // Un = kron(r0, r1) @ U
        C2 Un[4][4];
#pragma unroll
        for (int a = 0; a < 2; a++)
#pragma unroll
            for (int b = 0; b < 2; b++) {
                int i = 2*a + b;
#pragma unroll
                for (int j = 0; j < 4; j++) {
                    C2 acc = {0.f, 0.f};
#pragma unroll
                    for (int c = 0; c < 2; c++)
#pragma unroll
                        for (int d = 0; d < 2; d++) {
                            int k = 2*c + d;
                            C2 kij = cmul(r[0][a][c], r[1][b][d]);
                            acc = cadd(acc, cmul(kij, U[k][j]));
                        }
                    Un[i][j] = acc;
                }
            }
        // CNOT01: swap rows 2,3.  CNOT10: swap rows 1,3.
#pragma unroll
        for (int j = 0; j < 4; j++) { C2 t = Un[2][j]; Un[2][j] = Un[3][j]; Un[3][j] = t; }
#pragma unroll
        for (int j = 0; j < 4; j++) { C2 t = Un[1][j]; Un[1][j] = Un[3][j]; Un[3][j] = t; }
#pragma unroll
        for (int i = 0; i < 4; i++)
#pragma unroll
            for (int j = 0; j < 4; j++)
                U[i][j] = Un[i][j];
    }

    float w0 = fc_w[0];
    // A[i][j] = fc_w * Re( sum_k conj(U[k][i]) * D[k] * U[k][j] ), D = (+1,+1,-1,-1)
    float A[16];
#pragma unroll
    for (int i = 0; i < 4; i++)
#pragma unroll
        for (int j = 0; j < 4; j++) {
            float acc = 0.f;
#pragma unroll
            for (int k = 0; k < 4; k++) {
                float d = (k < 2) ? 1.f : -1.f;
                acc += d * (U[k][i].re * U[k][j].re + U[k][i].im * U[k][j].im);
            }
            A[i*4 + j] = w0 * acc;
        }

    // Reduce quadratic form in (c0,s0)x(c1,s1) half-angle products to
    // bilinear form in (1, cos x0, sin x0) x (1, cos x1, sin x1).
    float A00 = A[0],  A11 = A[5],  A22 = A[10], A33 = A[15];
    float a01 = A[1] + A[4];    // v0*v1 = c0^2 * c1 s1
    float a23 = A[11] + A[14];  // v2*v3 = s0^2 * c1 s1
    float a02 = A[2] + A[8];    // v0*v2 = c0 s0 * c1^2
    float a13 = A[7] + A[13];   // v1*v3 = c0 s0 * s1^2
    float a03 = A[3] + A[12];   // v0*v3 = c0 s0 * c1 s1
    float a12 = A[6] + A[9];    // v1*v2 = c0 s0 * c1 s1

    K[0] = 0.25f * (A00 + A11 + A22 + A33) + fc_b[0];
    K[1] = 0.25f * (A00 + A11 - A22 - A33);   // * cos x0
    K[2] = 0.25f * (a02 + a13);               // * sin x0
    K[3] = 0.25f * (A00 - A11 + A22 - A33);   // * cos x1
    K[4] = 0.25f * (A00 - A11 - A22 + A33);   // * cos x0 cos x1
    K[5] = 0.25f * (a02 - a13);               // * sin x0 cos x1
    K[6] = 0.25f * (a01 + a23);               // * sin x1
    K[7] = 0.25f * (a01 - a23);               // * cos x0 sin x1
    K[8] = 0.25f * (a03 + a12);               // * sin x0 sin x1
}

__global__ void qnn_setup_kernel(const float* __restrict__ qp,
                                 const float* __restrict__ fc_w,
                                 const float* __restrict__ fc_b,
                                 float* __restrict__ Kout) {
    float K[9];
    qnn_build_K(qp, fc_w, fc_b, K);
    if (threadIdx.x == 0) {
#pragma unroll
        for (int i = 0; i < 9; i++) Kout[i] = K[i];
    }
}

__device__ inline float qnn_eval(float x0, float x1,
                                 float K0, float K1, float K2,
                                 float K3, float K4, float K5,
                                 float K6, float K7, float K8) {
    float s0, c0, s1, c1;
    __sincosf(x0, &s0, &c0);
    __sincosf(x1, &s1, &c1);
    float e0 = fmaf(K2, s0, fmaf(K1, c0, K0));
    float e1 = fmaf(K5, s0, fmaf(K4, c0, K3));
    float e2 = fmaf(K8, s0, fmaf(K7, c0, K6));
    return fmaf(s1, e2, fmaf(c1, e1, e0));
}

__global__ __launch_bounds__(256) void qnn_stream_kernel(
        const float4* __restrict__ x,       // [B/2] float4 == [B,2] floats
        const float* __restrict__ Kin,      // [9] in workspace
        float4* __restrict__ out,           // [B/4] float4 == [B] floats
        int n4) {                           // B/4
    // Uniform, read-only -> scalar loads; hoisted out of the loop.
    float K0 = Kin[0], K1 = Kin[1], K2 = Kin[2];
    float K3 = Kin[3], K4 = Kin[4], K5 = Kin[5];
    float K6 = Kin[6], K7 = Kin[7], K8 = Kin[8];

    int stride = gridDim.x * blockDim.x;
    for (int t = blockIdx.x * blockDim.x + threadIdx.x; t < n4; t += stride) {
        float4 xa = x[2*t];
        float4 xb = x[2*t + 1];
        float4 o;
        o.x = qnn_eval(xa.x, xa.y, K0,K1,K2,K3,K4,K5,K6,K7,K8);
        o.y = qnn_eval(xa.z, xa.w, K0,K1,K2,K3,K4,K5,K6,K7,K8);
        o.z = qnn_eval(xb.x, xb.y, K0,K1,K2,K3,K4,K5,K6,K7,K8);
        o.w = qnn_eval(xb.z, xb.w, K0,K1,K2,K3,K4,K5,K6,K7,K8);
        out[t] = o;
    }
}

// Fallback: single fused kernel (per-thread K build) if no workspace.
__global__ __launch_bounds__(256) void qnn_fused_kernel(
        const float4* __restrict__ x,
        const float* __restrict__ qp,
        const float* __restrict__ fc_w,
        const float* __restrict__ fc_b,
        float4* __restrict__ out,
        int n4) {
    float K[9];
    qnn_build_K(qp, fc_w, fc_b, K);
    int stride = gridDim.x * blockDim.x;
    for (int t = blockIdx.x * blockDim.x + threadIdx.x; t < n4; t += stride) {
        float4 xa = x[2*t];
        float4 xb = x[2*t + 1];
        float4 o;
        o.x = qnn_eval(xa.x, xa.y, K[0],K[1],K[2],K[3],K[4],K[5],K[6],K[7],K[8]);
        o.y = qnn_eval(xa.z, xa.w, K[0],K[1],K[2],K[3],K[4],K[5],K[6],K[7],K[8]);
        o.z = qnn_eval(xb.x, xb.y, K[0],K[1],K[2],K[3],K[4],K[5],K[6],K[7],K[8]);
        o.w = qnn_eval(xb.z, xb.w, K[0],K[1],K[2],K[3],K[4],K[5],K[6],K[7],K[8]);
        out[t] = o;
    }
}

extern "C" void kernel_launch(void* const* d_in, const int* in_sizes, int n_in,
                              void* d_out, int out_size, void* d_ws, size_t ws_size,
                              hipStream_t stream) {
    const float* x    = (const float*)d_in[0];   // [B, 2] float32
    const float* qp   = (const float*)d_in[1];   // [2, 2, 3] float32
    const float* fc_w = (const float*)d_in[2];   // [1, 1] float32
    const float* fc_b = (const float*)d_in[3];   // [1] float32
    float* out = (float*)d_out;                  // [B, 1] float32

    int n  = in_sizes[0] / 2;   // batch size
    int n4 = n / 4;

    int block = 256;
    int grid  = (n4 + block - 1) / block;
    if (grid > 2048) grid = 2048;   // 8 blocks/CU; lean kernel -> one resident round

    if (ws_size >= 64 && d_ws != nullptr) {
        float* Kws = (float*)d_ws;
        qnn_setup_kernel<<<1, 64, 0, stream>>>(qp, fc_w, fc_b, Kws);
        qnn_stream_kernel<<<grid, block, 0, stream>>>(
            (const float4*)x, Kws, (float4*)out, n4);
    } else {
        qnn_fused_kernel<<<grid, block, 0, stream>>>(
            (const float4*)x, qp, fc_w, fc_b, (float4*)out, n4);
    }
}

// Round 2
// 74.612 us; speedup vs baseline: 1.1011x; 1.1011x over previous
//
#include <hip/hip_runtime.h>

// ---------------------------------------------------------------------------
// QNNClassifier: 2-qubit StronglyEntanglingLayers + <Z0> + Linear(1,1)
//
// R5 design: ONE dispatch (R4's two-dispatch split regressed +6us: dependent
// setup launch + drain costs more than the redundant build it removed).
// Per-thread K-build (runs once per resident wave, concurrently, ~0.5us) +
// 9-coefficient trig-reduced inner loop:
//   ev = (K0 + K1*cos x0 + K2*sin x0)
//      + cos x1 * (K3 + K4*cos x0 + K5*sin x0)
//      + sin x1 * (K6 + K7*cos x0 + K8*sin x0)
// (fc_w folded into K, fc_b folded into K0). Per element: 2 __sincosf + 8 FMA
// vs R3's 2 sincos + ~20 FMA.
//
// grid=1024 (== resident capacity at 4 blocks/CU with VGPR~100): the
// redundant K rebuild runs in ONE concurrent round device-wide, then
// grid-stride streaming of 16.8 MiB in / 8.4 MiB out (floor ~4us @ 6.3TB/s).
// ---------------------------------------------------------------------------

struct C2 { float re, im; };
__device__ inline C2 cmul(C2 a, C2 b) { return {a.re*b.re - a.im*b.im, a.re*b.im + a.im*b.re}; }
__device__ inline C2 cadd(C2 a, C2 b) { return {a.re + b.re, a.im + b.im}; }

// Build the 9 trig coefficients K[0..8] (fc_w folded in, fc_b added to K0).
__device__ inline void qnn_build_K(const float* __restrict__ qp,
                                   const float* __restrict__ fc_w,
                                   const float* __restrict__ fc_b,
                                   float* __restrict__ K) {
    C2 U[4][4];
#pragma unroll
    for (int i = 0; i < 4; i++)
#pragma unroll
        for (int j = 0; j < 4; j++)
            U[i][j] = { (i == j) ? 1.f : 0.f, 0.f };

#pragma unroll
    for (int l = 0; l < 2; l++) {
        C2 r[2][2][2];  // [wire][row][col]
#pragma unroll
        for (int w = 0; w < 2; w++) {
            float phi = qp[(l*2 + w)*3 + 0];
            float th  = qp[(l*2 + w)*3 + 1];
            float om  = qp[(l*2 + w)*3 + 2];
            float c, s, epre, epim, emre, emim;
            __sincosf(0.5f * th, &s, &c);
            __sincosf(-0.5f * (phi + om), &epim, &epre);   // ep = e^{-i(phi+om)/2}
            __sincosf( 0.5f * (phi - om), &emim, &emre);   // em = e^{ i(phi-om)/2}
            r[w][0][0] = {  epre * c,  epim * c };
            r[w][0][1] = { -emre * s, -emim * s };
            r[w][1][0] = {  emre * s, -emim * s };   // conj(em)*s
            r[w][1][1] = {  epre * c, -epim * c };   // conj(ep)*c
        }
        // Un = kron(r0, r1) @ U
        C2 Un[4][4];
#pragma unroll
        for (int a = 0; a < 2; a++)
#pragma unroll
            for (int b = 0; b < 2; b++) {
                int i = 2*a + b;
#pragma unroll
                for (int j = 0; j < 4; j++) {
                    C2 acc = {0.f, 0.f};
#pragma unroll
                    for (int c = 0; c < 2; c++)
#pragma unroll
                        for (int d = 0; d < 2; d++) {
                            int k = 2*c + d;
                            C2 kij = cmul(r[0][a][c], r[1][b][d]);
                            acc = cadd(acc, cmul(kij, U[k][j]));
                        }
                    Un[i][j] = acc;
                }
            }
        // CNOT01: swap rows 2,3.  CNOT10: swap rows 1,3.
#pragma unroll
        for (int j = 0; j < 4; j++) { C2 t = Un[2][j]; Un[2][j] = Un[3][j]; Un[3][j] = t; }
#pragma unroll
        for (int j = 0; j < 4; j++) { C2 t = Un[1][j]; Un[1][j] = Un[3][j]; Un[3][j] = t; }
#pragma unroll
        for (int i = 0; i < 4; i++)
#pragma unroll
            for (int j = 0; j < 4; j++)
                U[i][j] = Un[i][j];
    }

    float w0 = fc_w[0];
    // A[i][j] = fc_w * Re( sum_k conj(U[k][i]) * D[k] * U[k][j] ), D = (+1,+1,-1,-1)
    float A[16];
#pragma unroll
    for (int i = 0; i < 4; i++)
#pragma unroll
        for (int j = 0; j < 4; j++) {
            float acc = 0.f;
#pragma unroll
            for (int k = 0; k < 4; k++) {
                float d = (k < 2) ? 1.f : -1.f;
                acc += d * (U[k][i].re * U[k][j].re + U[k][i].im * U[k][j].im);
            }
            A[i*4 + j] = w0 * acc;
        }

    // Reduce quadratic form in (c0,s0)x(c1,s1) half-angle products to
    // bilinear form in (1, cos x0, sin x0) x (1, cos x1, sin x1):
    //   c^2 = (1+cos x)/2, s^2 = (1-cos x)/2, c*s = sin(x)/2.
    float A00 = A[0],  A11 = A[5],  A22 = A[10], A33 = A[15];
    float a01 = A[1] + A[4];    // v0*v1 = c0^2 * c1 s1
    float a23 = A[11] + A[14];  // v2*v3 = s0^2 * c1 s1
    float a02 = A[2] + A[8];    // v0*v2 = c0 s0 * c1^2
    float a13 = A[7] + A[13];   // v1*v3 = c0 s0 * s1^2
    float a03 = A[3] + A[12];   // v0*v3 = c0 s0 * c1 s1
    float a12 = A[6] + A[9];    // v1*v2 = c0 s0 * c1 s1

    K[0] = 0.25f * (A00 + A11 + A22 + A33) + fc_b[0];
    K[1] = 0.25f * (A00 + A11 - A22 - A33);   // * cos x0
    K[2] = 0.25f * (a02 + a13);               // * sin x0
    K[3] = 0.25f * (A00 - A11 + A22 - A33);   // * cos x1
    K[4] = 0.25f * (A00 - A11 - A22 + A33);   // * cos x0 cos x1
    K[5] = 0.25f * (a02 - a13);               // * sin x0 cos x1
    K[6] = 0.25f * (a01 + a23);               // * sin x1
    K[7] = 0.25f * (a01 - a23);               // * cos x0 sin x1
    K[8] = 0.25f * (a03 + a12);               // * sin x0 sin x1
}

__device__ inline float qnn_eval(float x0, float x1, const float* __restrict__ K) {
    float s0, c0, s1, c1;
    __sincosf(x0, &s0, &c0);
    __sincosf(x1, &s1, &c1);
    float e0 = fmaf(K[2], s0, fmaf(K[1], c0, K[0]));
    float e1 = fmaf(K[5], s0, fmaf(K[4], c0, K[3]));
    float e2 = fmaf(K[8], s0, fmaf(K[7], c0, K[6]));
    return fmaf(s1, e2, fmaf(c1, e1, e0));
}

__global__ __launch_bounds__(256) void qnn_fused_kernel(
        const float4* __restrict__ x,       // [B/2] float4 == [B,2] floats
        const float* __restrict__ qp,       // [2,2,3]
        const float* __restrict__ fc_w,     // [1,1]
        const float* __restrict__ fc_b,     // [1]
        float4* __restrict__ out,           // [B/4] float4 == [B] floats
        int n4) {                           // B/4
    float K[9];
    qnn_build_K(qp, fc_w, fc_b, K);

    int stride = gridDim.x * blockDim.x;
    for (int t = blockIdx.x * blockDim.x + threadIdx.x; t < n4; t += stride) {
        float4 xa = x[2*t];
        float4 xb = x[2*t + 1];
        float4 o;
        o.x = qnn_eval(xa.x, xa.y, K);
        o.y = qnn_eval(xa.z, xa.w, K);
        o.z = qnn_eval(xb.x, xb.y, K);
        o.w = qnn_eval(xb.z, xb.w, K);
        out[t] = o;
    }
}

extern "C" void kernel_launch(void* const* d_in, const int* in_sizes, int n_in,
                              void* d_out, int out_size, void* d_ws, size_t ws_size,
                              hipStream_t stream) {
    const float* x    = (const float*)d_in[0];   // [B, 2] float32
    const float* qp   = (const float*)d_in[1];   // [2, 2, 3] float32
    const float* fc_w = (const float*)d_in[2];   // [1, 1] float32
    const float* fc_b = (const float*)d_in[3];   // [1] float32
    float* out = (float*)d_out;                  // [B, 1] float32

    int n  = in_sizes[0] / 2;   // batch size
    int n4 = n / 4;

    // 1024 blocks == one resident round at ~4 blocks/CU (VGPR-capped by the
    // K-build phase): redundant build costs one concurrent ~1us, then pure
    // streaming. Single dispatch — R4's setup+stream split cost +6us in
    // dependent launch/drain overhead.
    int block = 256;
    int grid  = 1024;
    qnn_fused_kernel<<<grid, block, 0, stream>>>(
        (const float4*)x, qp, fc_w, fc_b, (float4*)out, n4);
}

// Round 3
// 73.151 us; speedup vs baseline: 1.1231x; 1.0200x over previous
//
#include <hip/hip_runtime.h>

// ---------------------------------------------------------------------------
// QNNClassifier: 2-qubit StronglyEntanglingLayers + <Z0> + Linear(1,1)
//
// R6 design: ONE dispatch (split regressed +6us in R4). 9-coefficient
// trig-reduced form (R5). New in R6: the two grid-stride iterations are
// straight-lined and their 4 float4 loads are issued BEFORE the redundant
// per-thread K-build, so the ~2400-cycle dependent build chain overlaps the
// first loads' HBM latency instead of serializing ahead of the stream.
//
//   ev = (K0 + K1*cos x0 + K2*sin x0)
//      + cos x1 * (K3 + K4*cos x0 + K5*sin x0)
//      + sin x1 * (K6 + K7*cos x0 + K8*sin x0)
// (fc_w folded into K, fc_b folded into K0.)
//
// grid=1024, block=256: 262144 threads == one resident round at 4 blocks/CU
// (VGPR in the 65-128 band), each thread produces exactly 2 float4 outputs
// for B=2^21 (n4=524288). Guarded straight-line + tail loop keeps it correct
// for any n4.
// ---------------------------------------------------------------------------

struct C2 { float re, im; };
__device__ inline C2 cmul(C2 a, C2 b) { return {a.re*b.re - a.im*b.im, a.re*b.im + a.im*b.re}; }
__device__ inline C2 cadd(C2 a, C2 b) { return {a.re + b.re, a.im + b.im}; }

// Build the 9 trig coefficients K[0..8] (fc_w folded in, fc_b added to K0).
__device__ inline void qnn_build_K(const float* __restrict__ qp,
                                   const float* __restrict__ fc_w,
                                   const float* __restrict__ fc_b,
                                   float* __restrict__ K) {
    C2 U[4][4];
#pragma unroll
    for (int i = 0; i < 4; i++)
#pragma unroll
        for (int j = 0; j < 4; j++)
            U[i][j] = { (i == j) ? 1.f : 0.f, 0.f };

#pragma unroll
    for (int l = 0; l < 2; l++) {
        C2 r[2][2][2];  // [wire][row][col]
#pragma unroll
        for (int w = 0; w < 2; w++) {
            float phi = qp[(l*2 + w)*3 + 0];
            float th  = qp[(l*2 + w)*3 + 1];
            float om  = qp[(l*2 + w)*3 + 2];
            float c, s, epre, epim, emre, emim;
            __sincosf(0.5f * th, &s, &c);
            __sincosf(-0.5f * (phi + om), &epim, &epre);   // ep = e^{-i(phi+om)/2}
            __sincosf( 0.5f * (phi - om), &emim, &emre);   // em = e^{ i(phi-om)/2}
            r[w][0][0] = {  epre * c,  epim * c };
            r[w][0][1] = { -emre * s, -emim * s };
            r[w][1][0] = {  emre * s, -emim * s };   // conj(em)*s
            r[w][1][1] = {  epre * c, -epim * c };   // conj(ep)*c
        }
        // Un = kron(r0, r1) @ U
        C2 Un[4][4];
#pragma unroll
        for (int a = 0; a < 2; a++)
#pragma unroll
            for (int b = 0; b < 2; b++) {
                int i = 2*a + b;
#pragma unroll
                for (int j = 0; j < 4; j++) {
                    C2 acc = {0.f, 0.f};
#pragma unroll
                    for (int c = 0; c < 2; c++)
#pragma unroll
                        for (int d = 0; d < 2; d++) {
                            int k = 2*c + d;
                            C2 kij = cmul(r[0][a][c], r[1][b][d]);
                            acc = cadd(acc, cmul(kij, U[k][j]));
                        }
                    Un[i][j] = acc;
                }
            }
        // CNOT01: swap rows 2,3.  CNOT10: swap rows 1,3.
#pragma unroll
        for (int j = 0; j < 4; j++) { C2 t = Un[2][j]; Un[2][j] = Un[3][j]; Un[3][j] = t; }
#pragma unroll
        for (int j = 0; j < 4; j++) { C2 t = Un[1][j]; Un[1][j] = Un[3][j]; Un[3][j] = t; }
#pragma unroll
        for (int i = 0; i < 4; i++)
#pragma unroll
            for (int j = 0; j < 4; j++)
                U[i][j] = Un[i][j];
    }

    float w0 = fc_w[0];
    // A[i][j] = fc_w * Re( sum_k conj(U[k][i]) * D[k] * U[k][j] ), D = (+1,+1,-1,-1)
    float A[16];
#pragma unroll
    for (int i = 0; i < 4; i++)
#pragma unroll
        for (int j = 0; j < 4; j++) {
            float acc = 0.f;
#pragma unroll
            for (int k = 0; k < 4; k++) {
                float d = (k < 2) ? 1.f : -1.f;
                acc += d * (U[k][i].re * U[k][j].re + U[k][i].im * U[k][j].im);
            }
            A[i*4 + j] = w0 * acc;
        }

    // Reduce quadratic form in (c0,s0)x(c1,s1) half-angle products to
    // bilinear form in (1, cos x0, sin x0) x (1, cos x1, sin x1):
    //   c^2 = (1+cos x)/2, s^2 = (1-cos x)/2, c*s = sin(x)/2.
    float A00 = A[0],  A11 = A[5],  A22 = A[10], A33 = A[15];
    float a01 = A[1] + A[4];    // v0*v1 = c0^2 * c1 s1
    float a23 = A[11] + A[14];  // v2*v3 = s0^2 * c1 s1
    float a02 = A[2] + A[8];    // v0*v2 = c0 s0 * c1^2
    float a13 = A[7] + A[13];   // v1*v3 = c0 s0 * s1^2
    float a03 = A[3] + A[12];   // v0*v3 = c0 s0 * c1 s1
    float a12 = A[6] + A[9];    // v1*v2 = c0 s0 * c1 s1

    K[0] = 0.25f * (A00 + A11 + A22 + A33) + fc_b[0];
    K[1] = 0.25f * (A00 + A11 - A22 - A33);   // * cos x0
    K[2] = 0.25f * (a02 + a13);               // * sin x0
    K[3] = 0.25f * (A00 - A11 + A22 - A33);   // * cos x1
    K[4] = 0.25f * (A00 - A11 - A22 + A33);   // * cos x0 cos x1
    K[5] = 0.25f * (a02 - a13);               // * sin x0 cos x1
    K[6] = 0.25f * (a01 + a23);               // * sin x1
    K[7] = 0.25f * (a01 - a23);               // * cos x0 sin x1
    K[8] = 0.25f * (a03 + a12);               // * sin x0 sin x1
}

__device__ inline float qnn_eval(float x0, float x1, const float* __restrict__ K) {
    float s0, c0, s1, c1;
    __sincosf(x0, &s0, &c0);
    __sincosf(x1, &s1, &c1);
    float e0 = fmaf(K[2], s0, fmaf(K[1], c0, K[0]));
    float e1 = fmaf(K[5], s0, fmaf(K[4], c0, K[3]));
    float e2 = fmaf(K[8], s0, fmaf(K[7], c0, K[6]));
    return fmaf(s1, e2, fmaf(c1, e1, e0));
}

__device__ inline float4 qnn_eval4(float4 xa, float4 xb, const float* __restrict__ K) {
    float4 o;
    o.x = qnn_eval(xa.x, xa.y, K);
    o.y = qnn_eval(xa.z, xa.w, K);
    o.z = qnn_eval(xb.x, xb.y, K);
    o.w = qnn_eval(xb.z, xb.w, K);
    return o;
}

__global__ __launch_bounds__(256) void qnn_fused_kernel(
        const float4* __restrict__ x,       // [B/2] float4 == [B,2] floats
        const float* __restrict__ qp,       // [2,2,3]
        const float* __restrict__ fc_w,     // [1,1]
        const float* __restrict__ fc_b,     // [1]
        float4* __restrict__ out,           // [B/4] float4 == [B] floats
        int n4) {                           // B/4
    int stride = gridDim.x * blockDim.x;
    int t0 = blockIdx.x * blockDim.x + threadIdx.x;
    int t1 = t0 + stride;

    // Issue BOTH iterations' loads before the K-build so the ~2400-cycle
    // dependent build chain overlaps the loads' HBM latency.
    bool v0 = t0 < n4, v1 = t1 < n4;
    float4 xa0, xb0, xa1, xb1;
    if (v0) { xa0 = x[2*t0]; xb0 = x[2*t0 + 1]; }
    if (v1) { xa1 = x[2*t1]; xb1 = x[2*t1 + 1]; }

    float K[9];
    qnn_build_K(qp, fc_w, fc_b, K);

    if (v0) out[t0] = qnn_eval4(xa0, xb0, K);
    if (v1) out[t1] = qnn_eval4(xa1, xb1, K);

    // Tail (empty for B=2^21 with grid 1024 x 256): generic grid-stride.
    for (int t = t1 + stride; t < n4; t += stride) {
        float4 xa = x[2*t];
        float4 xb = x[2*t + 1];
        out[t] = qnn_eval4(xa, xb, K);
    }
}

extern "C" void kernel_launch(void* const* d_in, const int* in_sizes, int n_in,
                              void* d_out, int out_size, void* d_ws, size_t ws_size,
                              hipStream_t stream) {
    const float* x    = (const float*)d_in[0];   // [B, 2] float32
    const float* qp   = (const float*)d_in[1];   // [2, 2, 3] float32
    const float* fc_w = (const float*)d_in[2];   // [1, 1] float32
    const float* fc_b = (const float*)d_in[3];   // [1] float32
    float* out = (float*)d_out;                  // [B, 1] float32

    int n  = in_sizes[0] / 2;   // batch size
    int n4 = n / 4;

    // 1024 blocks == one resident round at ~4 blocks/CU (VGPR 65-128 band):
    // the redundant K rebuild runs in ONE concurrent round device-wide and
    // overlaps the hoisted first loads; then pure streaming of
    // 16.8 MiB in / 8.4 MiB out (floor ~4us @ 6.3 TB/s).
    int block = 256;
    int grid  = 1024;
    qnn_fused_kernel<<<grid, block, 0, stream>>>(
        (const float4*)x, qp, fc_w, fc_b, (float4*)out, n4);
}